// Round 1
// baseline (136.048 us; speedup 1.0000x reference)
//
#include <hip/hip_runtime.h>
#include <math.h>

// ConsistencyLoss: KL( softmax(soft/T) || softmax(logits/T) ) * T^2, batchmean.
// B = 4,194,304, C = 5, T = 3.
//
// R7: remove LDS staging entirely. Logits have ZERO reuse (each byte read
// once), so the 40KB tile + global_load_lds + __syncthreads() was pure
// overhead: every block drained vmcnt(0) on its whole 40KB before ANY
// compute, and 40KB LDS capped residency at 4 blocks/CU -> latency-bound
// rounds (134 us = 751 GB/s, 8x above the ~16 us HBM floor).
// Now: pure streaming. Each thread owns 2 quads (8 samples), issues all
// 12 float4 loads up front (5 logit-vec4 + 1 score-vec4 per quad, 80B
// contiguous per quad -> a wave's loads cover a contiguous span, every
// line fully consumed via L1). No barrier before the reduction; latency
// hidden by TLP (no LDS -> occupancy VGPR-limited only) + 12-load ILP.

constexpr int   kC     = 5;
constexpr float kInvT  = 1.0f / 3.0f;
constexpr float kExp13 = 1.3956124250860895f;   // e^{1/3}
constexpr int   kBatch = 4194304;

constexpr int kThreads        = 256;
constexpr int kQuadsPerThread = 2;
constexpr int kQuadsPerBlock  = kThreads * kQuadsPerThread;        // 512
constexpr int kBlocks         = (kBatch / 4) / kQuadsPerBlock;     // 2048

__device__ __forceinline__ float kl_quad(float4 P0, float4 P1, float4 P2,
                                         float4 P3, float4 P4, float4 s4) {
    const float v[20] = {P0.x, P0.y, P0.z, P0.w,
                         P1.x, P1.y, P1.z, P1.w,
                         P2.x, P2.y, P2.z, P2.w,
                         P3.x, P3.y, P3.z, P3.w,
                         P4.x, P4.y, P4.z, P4.w};
    const float ss[4] = {s4.x, s4.y, s4.z, s4.w};

    float acc = 0.0f;
    #pragma unroll
    for (int r = 0; r < 4; ++r) {
        const float s  = ss[r];
        const float l0 = v[r * 5 + 0], l1 = v[r * 5 + 1], l2 = v[r * 5 + 2],
                    l3 = v[r * 5 + 3], l4 = v[r * 5 + 4];

        // --- soft target geometry (matches reference exactly) ---
        const float sc     = fminf(fmaxf(s * 5.0f, 0.0f), 4.0f);
        const int   idx    = (int)sc;                    // floor, s >= 0
        const float center = ((float)idx + 0.5f) * 0.2f;
        float       d      = fabsf(s - center) * 5.0f;
        const bool  lo     = (idx > 0) && (s < center);
        const bool  hi     = (idx < kC - 1) && (s > center);
        const bool  nb     = lo || hi;
        d = nb ? d : 0.0f;
        const int nbi = idx + (hi ? 1 : 0) - (lo ? 1 : 0);

        // soft = {1-d at idx, d at nbi, 0 elsewhere};  e_main = e^{1/3}/e_nb
        const float e_nb   = __expf(d * kInvT);
        const float e_main = kExp13 * __builtin_amdgcn_rcpf(e_nb);

        const float S = l0 + l1 + l2 + l3 + l4;
        const float l_main = (idx == 0) ? l0 : (idx == 1) ? l1 :
                             (idx == 2) ? l2 : (idx == 3) ? l3 : l4;
        const float l_nb   = (nbi == 0) ? l0 : (nbi == 1) ? l1 :
                             (nbi == 2) ? l2 : (nbi == 3) ? l3 : l4;

        const float Zq = __expf(l0 * kInvT) + __expf(l1 * kInvT) +
                         __expf(l2 * kInvT) + __expf(l3 * kInvT) +
                         __expf(l4 * kInvT);

        const float Zp  = e_main + e_nb + 3.0f;
        const float rZp = __builtin_amdgcn_rcpf(Zp);
        const float Spa = e_main * (1.0f - d) + e_nb * d;
        const float Spl = e_main * l_main + e_nb * l_nb + (S - l_main - l_nb);

        acc += kInvT * (Spa - Spl) * rZp + __logf(Zq * rZp);
    }
    return acc;
}

__global__ __launch_bounds__(kThreads) void kl_partial_kernel(
    const float* __restrict__ score,
    const float* __restrict__ logits,
    float* __restrict__ partial) {

    const int t = threadIdx.x;
    const int wave = t >> 6;                     // 0..3
    const int lane = t & 63;

    const size_t qA = (size_t)blockIdx.x * kQuadsPerBlock + t;
    const size_t qB = qA + kThreads;

    const float4* __restrict__ glog = reinterpret_cast<const float4*>(logits);
    const float4* __restrict__ gsc  = reinterpret_cast<const float4*>(score);

    // Issue ALL loads before any compute: 12 independent global_load_dwordx4
    // per thread. Each quad's 5 logit-vec4s are 80B contiguous; the wave's
    // access set is a contiguous 5KB span per quad-group -> full line use.
    const size_t aA = qA * 5, aB = qB * 5;
    const float4 A0 = glog[aA + 0], A1 = glog[aA + 1], A2 = glog[aA + 2],
                 A3 = glog[aA + 3], A4 = glog[aA + 4];
    const float4 B0 = glog[aB + 0], B1 = glog[aB + 1], B2 = glog[aB + 2],
                 B3 = glog[aB + 3], B4 = glog[aB + 4];
    const float4 sA = gsc[qA];
    const float4 sB = gsc[qB];

    float acc = kl_quad(A0, A1, A2, A3, A4, sA)
              + kl_quad(B0, B1, B2, B3, B4, sB);

    // --- wave (64-lane) shuffle reduction ---
    #pragma unroll
    for (int off = 32; off > 0; off >>= 1) acc += __shfl_down(acc, off, 64);

    __shared__ float wsum[kThreads / 64];
    if (lane == 0) wsum[wave] = acc;
    __syncthreads();
    if (t == 0) {
        float b = 0.0f;
        #pragma unroll
        for (int w = 0; w < kThreads / 64; ++w) b += wsum[w];
        partial[blockIdx.x] = b;
    }
}

__global__ __launch_bounds__(256) void kl_final_kernel(
    const float* __restrict__ partial,
    float* __restrict__ out) {
    const int t = threadIdx.x;
    // 2048 partials = 512 float4s; thread t sums float4 t and t+256
    const float4* p4 = reinterpret_cast<const float4*>(partial);
    const float4 a = p4[t], b = p4[t + 256];
    float acc = a.x + a.y + a.z + a.w + b.x + b.y + b.z + b.w;

    #pragma unroll
    for (int off = 32; off > 0; off >>= 1) acc += __shfl_down(acc, off, 64);

    __shared__ float wsum[4];
    if ((t & 63) == 0) wsum[t >> 6] = acc;
    __syncthreads();
    if (t == 0) {
        out[0] = (wsum[0] + wsum[1] + wsum[2] + wsum[3]) * (9.0f / (float)kBatch);
    }
}

extern "C" void kernel_launch(void* const* d_in, const int* in_sizes, int n_in,
                              void* d_out, int out_size, void* d_ws, size_t ws_size,
                              hipStream_t stream) {
    const float* score  = (const float*)d_in[0];   // quality_score [B]
    const float* logits = (const float*)d_in[1];   // class_logits [B,5]
    float* out     = (float*)d_out;
    float* partial = (float*)d_ws;                 // kBlocks floats, rewritten every call

    kl_partial_kernel<<<kBlocks, kThreads, 0, stream>>>(score, logits, partial);
    kl_final_kernel<<<1, 256, 0, stream>>>(partial, out);
}